// Round 17
// baseline (175.897 us; speedup 1.0000x reference)
//
#include <hip/hip_runtime.h>
#include <hip/hip_fp16.h>
#include <math.h>

typedef __attribute__((ext_vector_type(8))) _Float16 f16x8;
typedef __attribute__((ext_vector_type(2))) __fp16 fp16x2;
typedef __attribute__((ext_vector_type(4))) float f32x4;

constexpr int D = 256;           // feature dim (K of GEMM)
constexpr int H = 128;           // hidden dim
constexpr int KSTEPS = D / 32;   // 8 MFMA k-steps
constexpr int BM = 128;          // rows per block

union FragH { uint4 u; f16x8 f; };
union H2U { fp16x2 h; unsigned int u; };

__device__ __forceinline__ unsigned int pkrtz(float a, float b) {
  H2U r; r.h = __builtin_amdgcn_cvt_pkrtz(a, b); return r.u;
}
__device__ __forceinline__ void gload16(const void* g, void* l) {
  __builtin_amdgcn_global_load_lds(
      (const __attribute__((address_space(1))) unsigned int*)g,
      (__attribute__((address_space(3))) unsigned int*)l, 16, 0, 0);
}
__device__ __forceinline__ void block_sync() {
  asm volatile("" ::: "memory");
  __builtin_amdgcn_s_barrier();
  asm volatile("" ::: "memory");
}

// ---- init: zero d_out + Z accumulator --------------------------------------
extern "C" __global__ void __launch_bounds__(256)
k_init(float* __restrict__ out, int out_size, float* __restrict__ zacc)
{
  const int i = blockIdx.x * 256 + threadIdx.x;
  if (i < out_size) out[i] = 0.0f;
  if (i == 0) *zacc = 0.0f;
}

// ---- Pre-pack W1 into per-lane MFMA B-fragment order (fp16 RTN) ------------
// Index g = (kstep*8 + htile)*64 + lane; element j: K = kstep*32+(lane>>4)*8+j,
// N(col) = htile*16 + (lane&15).
extern "C" __global__ void __launch_bounds__(256)
k_pack(const float* __restrict__ W1, uint4* __restrict__ pw)
{
  const int g = blockIdx.x * 256 + threadIdx.x;       // 0..4095
  const int c = g >> 9, ht = (g >> 6) & 7, l = g & 63;
  const int kbase = c * 32 + (l >> 4) * 8;
  const int col = ht * 16 + (l & 15);
  unsigned short q[8];
#pragma unroll
  for (int i = 0; i < 8; ++i) {
    const float v = W1[(size_t)(kbase + i) * H + col];
    const __half hh = __float2half(v);                 // RTN
    q[i] = __half_as_ushort(hh);
  }
  uint4 h4;
  h4.x = (unsigned)q[0] | ((unsigned)q[1] << 16);
  h4.y = (unsigned)q[2] | ((unsigned)q[3] << 16);
  h4.z = (unsigned)q[4] | ((unsigned)q[5] << 16);
  h4.w = (unsigned)q[6] | ((unsigned)q[7] << 16);
  pw[g] = h4;
}

// ---- Fused: fp16 MFMA scores -> w=exp(s) -> pooled, 3-buf 2-ahead pipeline -
// 4 waves (2x2): wave (rg,cg) computes rows rg*64..+63 x hidden cols cg*64..+63.
// Per iter c: vmcnt(4) {drains B(c) issued 1 kstep ago, S(c) issued 2 ksteps
// ago -> zero stall}, ONE barrier, then issue B(c+1) + STAGE(c+2) (safe after
// the barrier: everyone finished compute(c-1), the buffer being rewritten),
// then compute(c). S(c+1)+S(c+2) stay in flight during every compute phase.
extern "C" __global__ void __launch_bounds__(256, 3)
k_fused(const float* __restrict__ x, const int* __restrict__ batch,
        const uint4* __restrict__ pw, const float* __restrict__ b1,
        const float* __restrict__ W2, const float* __restrict__ b2,
        float* __restrict__ out, float* __restrict__ zacc, int N)
{
  __shared__ float4 xplane[3][1024];   // 3 bufs x 16 KB (16 planes x 64 x 16 B)
  __shared__ float sred[2][BM];        // cross-wave epilogue partials
  __shared__ float wlds[BM];           // per-row unnormalized weights

  const int t = threadIdx.x;
  const int l = t & 63;
  const int w = t >> 6;
  const int lg = l >> 4;      // k-group (0..3)
  const int lr = l & 15;      // M-row (A) / N-col (B,C)
  const int rg = w >> 1;      // row half (0..1)
  const int cg = w & 1;       // col half (0..1)
  const int n0 = blockIdx.x * BM;

  const char* xb = (const char*)x;

  // hoisted epilogue constants (retired before the steady-state vmcnt stream)
  float bvv[4], wvv[4];
#pragma unroll
  for (int h = 0; h < 4; ++h) {
    const int col = (cg * 4 + h) * 16 + lr;
    bvv[h] = b1[col];
    wvv[h] = W2[col];
  }
  const float b2v = b2[0];
  asm volatile("s_waitcnt vmcnt(0)" ::: "memory");   // clear prologue loads

  // stage x tile for kstep c into buffer buf (4 gload16 per thread)
  auto STAGE = [&](int buf, int c) {
#pragma unroll
    for (int i = 0; i < 4; ++i) {
      const int plane = i * 4 + w;
      const int g = plane >> 1, p = plane & 1;
      const int srow = min(n0 + g * 16 + lr, N - 1);   // clamp OOB (discarded)
      gload16(xb + (size_t)srow * 1024 + c * 128 + lg * 32 + p * 16,
              (char*)&xplane[buf][plane * 64 + l]);
    }
  };

  f32x4 acc[4][4] = {};   // [stripe s][local htile h]

  // prologue: B(0):4, S(0):4, S(1):4  (12 outstanding)
  FragH bw[4], nbw[4];
#pragma unroll
  for (int h = 0; h < 4; ++h)
    bw[h].u = pw[(cg * 4 + h) * 64 + l];
  STAGE(0, 0);
  STAGE(1, 1);

#pragma unroll 1
  for (int c = 0; c < KSTEPS; ++c) {
    const int cur = c % 3;
    if (c + 1 < KSTEPS) {
      // newest 4 outstanding = S(c+1); drains B(c) (1 kstep old) + S(c) (2 old)
      asm volatile("s_waitcnt vmcnt(4)" ::: "memory");
    } else {
      asm volatile("s_waitcnt vmcnt(0)" ::: "memory");
    }
    block_sync();   // single barrier per kstep

    // issue next B regs + stage 2 ahead (post-barrier => rewrite is race-free)
    if (c + 1 < KSTEPS) {
#pragma unroll
      for (int h = 0; h < 4; ++h)
        nbw[h].u = pw[((c + 1) * 8 + cg * 4 + h) * 64 + l];
      if (c + 2 < KSTEPS) STAGE((c + 2) % 3, c + 2);
    }

    // A fragments per stripe (conflict-free plane reads) -> fp16, MFMA
#pragma unroll
    for (int s = 0; s < 4; ++s) {
      const int g = rg * 4 + s;
      const float4 u0 = xplane[cur][(g * 2 + 0) * 64 + l];
      const float4 u1 = xplane[cur][(g * 2 + 1) * 64 + l];
      FragH a;
      a.u.x = pkrtz(u0.x, u0.y);
      a.u.y = pkrtz(u0.z, u0.w);
      a.u.z = pkrtz(u1.x, u1.y);
      a.u.w = pkrtz(u1.z, u1.w);
#pragma unroll
      for (int h = 0; h < 4; ++h)
        acc[s][h] = __builtin_amdgcn_mfma_f32_16x16x32_f16(a.f, bw[h].f, acc[s][h], 0, 0, 0);
    }
#pragma unroll
    for (int h = 0; h < 4; ++h) bw[h] = nbw[h];
  }

  // ---- epilogue: relu(h+b1)@W2 partials, cross-wave sum, w = exp(s) --------
#pragma unroll
  for (int s = 0; s < 4; ++s) {
#pragma unroll
    for (int r = 0; r < 4; ++r) {
      float p = 0.0f;
#pragma unroll
      for (int h = 0; h < 4; ++h)
        p = fmaf(fmaxf(acc[s][h][r] + bvv[h], 0.0f), wvv[h], p);
#pragma unroll
      for (int off = 1; off < 16; off <<= 1) p += __shfl_xor(p, off, 64);
      if (lr == 0) sred[cg][rg * 64 + s * 16 + lg * 4 + r] = p;
    }
  }
  __syncthreads();
  if (cg == 0) {                      // waves 0 and 2 finalize 64 rows each
    const int row = rg * 64 + l;
    const int node = n0 + row;
    const float sc = sred[0][row] + sred[1][row] + b2v;
    const float wgt = (node < N) ? __expf(sc) : 0.0f;
    wlds[row] = wgt;
    float zs = wgt;
#pragma unroll
    for (int off = 1; off < 64; off <<= 1) zs += __shfl_xor(zs, off, 64);
    if (l == 0) atomicAdd(zacc, zs);
  }
  __syncthreads();

  // ---- phase 2: pool own 128 rows (batch sorted); lane owns 4 columns ----
  {
    const int nStart = n0 + w * 32;
    const int nEnd = min(nStart + 32, N);
    if (nStart < nEnd) {
      float4 a4 = make_float4(0.f, 0.f, 0.f, 0.f);
      int bprev = batch[nStart];
      for (int n = nStart; n < nEnd; ++n) {
        const int b = batch[n];
        if (b != bprev) {
          float* o = out + (size_t)bprev * D + l * 4;
          atomicAdd(o + 0, a4.x); atomicAdd(o + 1, a4.y);
          atomicAdd(o + 2, a4.z); atomicAdd(o + 3, a4.w);
          a4 = make_float4(0.f, 0.f, 0.f, 0.f);
          bprev = b;
        }
        const float wgt = wlds[n - n0];
        const float4 xv = *reinterpret_cast<const float4*>(x + (size_t)n * D + l * 4);
        a4.x = fmaf(xv.x, wgt, a4.x);
        a4.y = fmaf(xv.y, wgt, a4.y);
        a4.z = fmaf(xv.z, wgt, a4.z);
        a4.w = fmaf(xv.w, wgt, a4.w);
      }
      float* o = out + (size_t)bprev * D + l * 4;
      atomicAdd(o + 0, a4.x); atomicAdd(o + 1, a4.y);
      atomicAdd(o + 2, a4.z); atomicAdd(o + 3, a4.w);
    }
  }
}

// ---- finish: out *= 1/Z ----------------------------------------------------
extern "C" __global__ void __launch_bounds__(256)
k_finish(float* __restrict__ out, const float* __restrict__ zacc, int size)
{
  const int i = blockIdx.x * 256 + threadIdx.x;
  if (i < size) out[i] *= (1.0f / *zacc);
}

extern "C" void kernel_launch(void* const* d_in, const int* in_sizes, int n_in,
                              void* d_out, int out_size, void* d_ws, size_t ws_size,
                              hipStream_t stream)
{
  const float* x     = (const float*)d_in[0];
  const int*   batch = (const int*)d_in[1];
  const float* W1 = (const float*)d_in[3];
  const float* b1 = (const float*)d_in[4];
  const float* W2 = (const float*)d_in[5];
  const float* b2 = (const float*)d_in[6];
  const int N = in_sizes[1];

  float* zacc = (float*)d_ws;
  uint4* pw   = (uint4*)((char*)d_ws + 256);            // 64 KB fp16 W frags

  k_init<<<(out_size + 255) / 256, 256, 0, stream>>>((float*)d_out, out_size, zacc);
  k_pack<<<16, 256, 0, stream>>>(W1, pw);

  const int g1 = (N + BM - 1) / BM;
  k_fused<<<g1, 256, 0, stream>>>(x, batch, pw, b1, W2, b2,
                                  (float*)d_out, zacc, N);

  k_finish<<<(out_size + 255) / 256, 256, 0, stream>>>((float*)d_out, zacc, out_size);
}

// Round 18
// 174.201 us; speedup vs baseline: 1.0097x; 1.0097x over previous
//
#include <hip/hip_runtime.h>
#include <hip/hip_fp16.h>
#include <math.h>

typedef __attribute__((ext_vector_type(8))) _Float16 f16x8;
typedef __attribute__((ext_vector_type(2))) __fp16 fp16x2;
typedef __attribute__((ext_vector_type(4))) float f32x4;

constexpr int D = 256;           // feature dim (K of GEMM)
constexpr int H = 128;           // hidden dim
constexpr int KSTEPS = D / 32;   // 8 MFMA k-steps
constexpr int BM = 128;          // rows per block

union FragH { uint4 u; f16x8 f; };
union H2U { fp16x2 h; unsigned int u; };

__device__ __forceinline__ unsigned int pkrtz(float a, float b) {
  H2U r; r.h = __builtin_amdgcn_cvt_pkrtz(a, b); return r.u;
}
__device__ __forceinline__ void gload16(const void* g, void* l) {
  __builtin_amdgcn_global_load_lds(
      (const __attribute__((address_space(1))) unsigned int*)g,
      (__attribute__((address_space(3))) unsigned int*)l, 16, 0, 0);
}
__device__ __forceinline__ void block_sync() {
  asm volatile("" ::: "memory");
  __builtin_amdgcn_s_barrier();
  asm volatile("" ::: "memory");
}

// ---- init: zero d_out + Z accumulator --------------------------------------
extern "C" __global__ void __launch_bounds__(256)
k_init(float* __restrict__ out, int out_size, float* __restrict__ zacc)
{
  const int i = blockIdx.x * 256 + threadIdx.x;
  if (i < out_size) out[i] = 0.0f;
  if (i == 0) *zacc = 0.0f;
}

// ---- Pre-pack W1 into per-lane MFMA B-fragment order (fp16 RTN) ------------
// Index g = (kstep*8 + htile)*64 + lane; element j: K = kstep*32+(lane>>4)*8+j,
// N(col) = htile*16 + (lane&15).
extern "C" __global__ void __launch_bounds__(256)
k_pack(const float* __restrict__ W1, uint4* __restrict__ pw)
{
  const int g = blockIdx.x * 256 + threadIdx.x;       // 0..4095
  const int c = g >> 9, ht = (g >> 6) & 7, l = g & 63;
  const int kbase = c * 32 + (l >> 4) * 8;
  const int col = ht * 16 + (l & 15);
  unsigned short q[8];
#pragma unroll
  for (int i = 0; i < 8; ++i) {
    const float v = W1[(size_t)(kbase + i) * H + col];
    const __half hh = __float2half(v);                 // RTN
    q[i] = __half_as_ushort(hh);
  }
  uint4 h4;
  h4.x = (unsigned)q[0] | ((unsigned)q[1] << 16);
  h4.y = (unsigned)q[2] | ((unsigned)q[3] << 16);
  h4.z = (unsigned)q[4] | ((unsigned)q[5] << 16);
  h4.w = (unsigned)q[6] | ((unsigned)q[7] << 16);
  pw[g] = h4;
}

// ---- Fused: fp16 MFMA scores -> w=exp(s) -> pooled; 3-buf pipeline + ------
// ---- CONVOY-BREAKING STAGGERED START (theory #10 test) ---------------------
// Blocks bid%3==1,2 sleep ~0.8/1.6us once at entry so the ~3 resident blocks
// per CU run phase-offset: one block's HBM fill overlaps the others' compute.
extern "C" __global__ void __launch_bounds__(256, 3)
k_fused(const float* __restrict__ x, const int* __restrict__ batch,
        const uint4* __restrict__ pw, const float* __restrict__ b1,
        const float* __restrict__ W2, const float* __restrict__ b2,
        float* __restrict__ out, float* __restrict__ zacc, int N)
{
  __shared__ float4 xplane[3][1024];   // 3 bufs x 16 KB (16 planes x 64 x 16 B)
  __shared__ float sred[2][BM];        // cross-wave epilogue partials
  __shared__ float wlds[BM];           // per-row unnormalized weights

  // de-phase resident blocks: one-time ~0.8us per step (s_sleep 25 = 1600 cyc)
  {
    const int ph = blockIdx.x % 3;
#pragma unroll 1
    for (int i = 0; i < ph; ++i)
      asm volatile("s_sleep 25" ::: "memory");
  }

  const int t = threadIdx.x;
  const int l = t & 63;
  const int w = t >> 6;
  const int lg = l >> 4;      // k-group (0..3)
  const int lr = l & 15;      // M-row (A) / N-col (B,C)
  const int rg = w >> 1;      // row half (0..1)
  const int cg = w & 1;       // col half (0..1)
  const int n0 = blockIdx.x * BM;

  const char* xb = (const char*)x;

  // hoisted epilogue constants (retired before the steady-state vmcnt stream)
  float bvv[4], wvv[4];
#pragma unroll
  for (int h = 0; h < 4; ++h) {
    const int col = (cg * 4 + h) * 16 + lr;
    bvv[h] = b1[col];
    wvv[h] = W2[col];
  }
  const float b2v = b2[0];
  asm volatile("s_waitcnt vmcnt(0)" ::: "memory");   // clear prologue loads

  // stage x tile for kstep c into buffer buf (4 gload16 per thread)
  auto STAGE = [&](int buf, int c) {
#pragma unroll
    for (int i = 0; i < 4; ++i) {
      const int plane = i * 4 + w;
      const int g = plane >> 1, p = plane & 1;
      const int srow = min(n0 + g * 16 + lr, N - 1);   // clamp OOB (discarded)
      gload16(xb + (size_t)srow * 1024 + c * 128 + lg * 32 + p * 16,
              (char*)&xplane[buf][plane * 64 + l]);
    }
  };

  f32x4 acc[4][4] = {};   // [stripe s][local htile h]

  // prologue: B(0):4, S(0):4, S(1):4  (12 outstanding)
  FragH bw[4], nbw[4];
#pragma unroll
  for (int h = 0; h < 4; ++h)
    bw[h].u = pw[(cg * 4 + h) * 64 + l];
  STAGE(0, 0);
  STAGE(1, 1);

#pragma unroll 1
  for (int c = 0; c < KSTEPS; ++c) {
    const int cur = c % 3;
    if (c + 1 < KSTEPS) {
      // newest 4 outstanding = S(c+1); drains B(c) (1 kstep old) + S(c) (2 old)
      asm volatile("s_waitcnt vmcnt(4)" ::: "memory");
    } else {
      asm volatile("s_waitcnt vmcnt(0)" ::: "memory");
    }
    block_sync();   // single barrier per kstep

    // issue next B regs + stage 2 ahead (post-barrier => rewrite is race-free)
    if (c + 1 < KSTEPS) {
#pragma unroll
      for (int h = 0; h < 4; ++h)
        nbw[h].u = pw[((c + 1) * 8 + cg * 4 + h) * 64 + l];
      if (c + 2 < KSTEPS) STAGE((c + 2) % 3, c + 2);
    }

    // A fragments per stripe (conflict-free plane reads) -> fp16, MFMA
#pragma unroll
    for (int s = 0; s < 4; ++s) {
      const int g = rg * 4 + s;
      const float4 u0 = xplane[cur][(g * 2 + 0) * 64 + l];
      const float4 u1 = xplane[cur][(g * 2 + 1) * 64 + l];
      FragH a;
      a.u.x = pkrtz(u0.x, u0.y);
      a.u.y = pkrtz(u0.z, u0.w);
      a.u.z = pkrtz(u1.x, u1.y);
      a.u.w = pkrtz(u1.z, u1.w);
#pragma unroll
      for (int h = 0; h < 4; ++h)
        acc[s][h] = __builtin_amdgcn_mfma_f32_16x16x32_f16(a.f, bw[h].f, acc[s][h], 0, 0, 0);
    }
#pragma unroll
    for (int h = 0; h < 4; ++h) bw[h] = nbw[h];
  }

  // ---- epilogue: relu(h+b1)@W2 partials, cross-wave sum, w = exp(s) --------
#pragma unroll
  for (int s = 0; s < 4; ++s) {
#pragma unroll
    for (int r = 0; r < 4; ++r) {
      float p = 0.0f;
#pragma unroll
      for (int h = 0; h < 4; ++h)
        p = fmaf(fmaxf(acc[s][h][r] + bvv[h], 0.0f), wvv[h], p);
#pragma unroll
      for (int off = 1; off < 16; off <<= 1) p += __shfl_xor(p, off, 64);
      if (lr == 0) sred[cg][rg * 64 + s * 16 + lg * 4 + r] = p;
    }
  }
  __syncthreads();
  if (cg == 0) {                      // waves 0 and 2 finalize 64 rows each
    const int row = rg * 64 + l;
    const int node = n0 + row;
    const float sc = sred[0][row] + sred[1][row] + b2v;
    const float wgt = (node < N) ? __expf(sc) : 0.0f;
    wlds[row] = wgt;
    float zs = wgt;
#pragma unroll
    for (int off = 1; off < 64; off <<= 1) zs += __shfl_xor(zs, off, 64);
    if (l == 0) atomicAdd(zacc, zs);
  }
  __syncthreads();

  // ---- phase 2: pool own 128 rows (batch sorted); lane owns 4 columns ----
  {
    const int nStart = n0 + w * 32;
    const int nEnd = min(nStart + 32, N);
    if (nStart < nEnd) {
      float4 a4 = make_float4(0.f, 0.f, 0.f, 0.f);
      int bprev = batch[nStart];
      for (int n = nStart; n < nEnd; ++n) {
        const int b = batch[n];
        if (b != bprev) {
          float* o = out + (size_t)bprev * D + l * 4;
          atomicAdd(o + 0, a4.x); atomicAdd(o + 1, a4.y);
          atomicAdd(o + 2, a4.z); atomicAdd(o + 3, a4.w);
          a4 = make_float4(0.f, 0.f, 0.f, 0.f);
          bprev = b;
        }
        const float wgt = wlds[n - n0];
        const float4 xv = *reinterpret_cast<const float4*>(x + (size_t)n * D + l * 4);
        a4.x = fmaf(xv.x, wgt, a4.x);
        a4.y = fmaf(xv.y, wgt, a4.y);
        a4.z = fmaf(xv.z, wgt, a4.z);
        a4.w = fmaf(xv.w, wgt, a4.w);
      }
      float* o = out + (size_t)bprev * D + l * 4;
      atomicAdd(o + 0, a4.x); atomicAdd(o + 1, a4.y);
      atomicAdd(o + 2, a4.z); atomicAdd(o + 3, a4.w);
    }
  }
}

// ---- finish: out *= 1/Z ----------------------------------------------------
extern "C" __global__ void __launch_bounds__(256)
k_finish(float* __restrict__ out, const float* __restrict__ zacc, int size)
{
  const int i = blockIdx.x * 256 + threadIdx.x;
  if (i < size) out[i] *= (1.0f / *zacc);
}

extern "C" void kernel_launch(void* const* d_in, const int* in_sizes, int n_in,
                              void* d_out, int out_size, void* d_ws, size_t ws_size,
                              hipStream_t stream)
{
  const float* x     = (const float*)d_in[0];
  const int*   batch = (const int*)d_in[1];
  const float* W1 = (const float*)d_in[3];
  const float* b1 = (const float*)d_in[4];
  const float* W2 = (const float*)d_in[5];
  const float* b2 = (const float*)d_in[6];
  const int N = in_sizes[1];

  float* zacc = (float*)d_ws;
  uint4* pw   = (uint4*)((char*)d_ws + 256);            // 64 KB fp16 W frags

  k_init<<<(out_size + 255) / 256, 256, 0, stream>>>((float*)d_out, out_size, zacc);
  k_pack<<<16, 256, 0, stream>>>(W1, pw);

  const int g1 = (N + BM - 1) / BM;
  k_fused<<<g1, 256, 0, stream>>>(x, batch, pw, b1, W2, b2,
                                  (float*)d_out, zacc, N);

  k_finish<<<(out_size + 255) / 256, 256, 0, stream>>>((float*)d_out, zacc, out_size);
}